// Round 9
// baseline (423.422 us; speedup 1.0000x reference)
//
#include <hip/hip_runtime.h>
#include <hip/hip_bf16.h>
#include <stdint.h>

#define PI_F 3.14159265358979f
#define EMBR 0.0275f
#define BATCH 1024
#define DIM 512
#define D2 1024
#define HID 2048
#define NB 30
#define K1 (NB * D2)          // 30720
#define NZ 8                  // i-chunk slices for rtrans GEMM

using short8 = __attribute__((ext_vector_type(8))) short;
using f32x4  = __attribute__((ext_vector_type(4))) float;

// s_waitcnt: vmcnt lo [3:0], expcnt [6:4]=7 (ignore), lgkmcnt [11:8]=0xF (ignore), vmcnt hi [15:14]
#define WAITVM(N) __builtin_amdgcn_s_waitcnt(((N) & 0xF) | (((N) >> 4) << 14) | (0x7 << 4) | (0xF << 8))
#define SCHED_FENCE() __builtin_amdgcn_sched_barrier(0)

__device__ __forceinline__ ushort f2bf(float f) {
  uint32_t u = __builtin_bit_cast(uint32_t, f);
  u += 0x7fffu + ((u >> 16) & 1u);   // RNE
  return (ushort)(u >> 16);
}

// async global->LDS, 16B per lane; LDS dest = wave-uniform base + lane*16
__device__ __forceinline__ void gld_lds16(const void* g, void* l) {
  __builtin_amdgcn_global_load_lds(
      (const __attribute__((address_space(1))) uint32_t*)(uintptr_t)g,
      (__attribute__((address_space(3))) uint32_t*)(uintptr_t)l, 16, 0, 0);
}

// ============ mega prep v2: wide-segment transpose | prep | 2x weight cvts ============
// Transpose tile 256(k) x 128(o): both HBM sides 512B segments (old: 128B writes).
// Phase 1: 4 float4 loads from 4 consecutive k-rows -> register 4x4 transpose ->
// ushort4 to LDS [o][k] (pitch 264 ushorts, 16B-aligned rows). Phase 2: b128 LDS
// reads + 16B global stores, 512B-contiguous RBt row runs. LDS bank conflicts on
// phase-1 writes (~1Kcy/block) are hidden under the ~22Kcy/block HBM budget.
#define TR2_BLKS 960                    // (K1/256=120) x (D2/128=8)
#define PREP_BLKS 1024
#define W1F4 (HID * D2 / 4)             // 524288
#define W2F4 (HID * HID / 4)            // 1048576
#define W0F4 (D2 * HID / 4)             // 524288
#define WA1F4 (DIM * D2 / 4)            // 131072
#define WA2F4 (D2 * DIM / 4)            // 131072
#define CVT2_BLKS ((W1F4 + W2F4 + W0F4 + WA1F4 + WA2F4) / 512)  // 4608 (2 f4/thread)
#define TPITCH 264                      // ushorts; 16B-aligned rows, 128*264*2 = 67584 B

__global__ __launch_bounds__(256) void mega_prep(
    const float* __restrict__ rel_base, ushort* __restrict__ RBt,
    const float* __restrict__ axis, const float* __restrict__ argp,
    const int* __restrict__ rel, const float* __restrict__ rel_att,
    const float* __restrict__ rel_ax, const float* __restrict__ rel_ar,
    float* __restrict__ attb, ushort* __restrict__ Ebf, ushort* __restrict__ h0,
    const float* __restrict__ W1, const float* __restrict__ W2,
    const float* __restrict__ W0, const float* __restrict__ Wa1,
    const float* __restrict__ Wa2,
    ushort* __restrict__ W1b, ushort* __restrict__ W2b, ushort* __restrict__ W0b,
    ushort* __restrict__ Wa1b, ushort* __restrict__ Wa2b) {
  __shared__ ushort tsT[128 * TPITCH];
  const int bid = blockIdx.x, t = threadIdx.x;
  if (bid < TR2_BLKS) {
    // tile k0..k0+255 (src rows) x o0..o0+127 (src cols); RBt[o][k] = bf16(rel_base[k][o])
    const int k0 = (bid >> 3) * 256, o0 = (bid & 7) * 128;
    const int qg  = (t >> 5) * 4;        // k-quad within 32-k pass group
    const int of4 = (t & 31) * 4;        // o offset (4 floats = 16B)
#pragma unroll
    for (int p = 0; p < 8; ++p) {
      const int kq = p * 32 + qg;
      const float* src = &rel_base[(size_t)(k0 + kq) * D2 + o0 + of4];
      float4 v0 = *(const float4*)(src);
      float4 v1 = *(const float4*)(src + D2);
      float4 v2 = *(const float4*)(src + 2 * D2);
      float4 v3 = *(const float4*)(src + 3 * D2);
      ushort4 w;
      w.x = f2bf(v0.x); w.y = f2bf(v1.x); w.z = f2bf(v2.x); w.w = f2bf(v3.x);
      *(ushort4*)&tsT[(of4 + 0) * TPITCH + kq] = w;
      w.x = f2bf(v0.y); w.y = f2bf(v1.y); w.z = f2bf(v2.y); w.w = f2bf(v3.y);
      *(ushort4*)&tsT[(of4 + 1) * TPITCH + kq] = w;
      w.x = f2bf(v0.z); w.y = f2bf(v1.z); w.z = f2bf(v2.z); w.w = f2bf(v3.z);
      *(ushort4*)&tsT[(of4 + 2) * TPITCH + kq] = w;
      w.x = f2bf(v0.w); w.y = f2bf(v1.w); w.z = f2bf(v2.w); w.w = f2bf(v3.w);
      *(ushort4*)&tsT[(of4 + 3) * TPITCH + kq] = w;
    }
    __syncthreads();
#pragma unroll
    for (int p = 0; p < 16; ++p) {
      const int orow = p * 8 + (t >> 5);
      const int kc = (t & 31) * 8;       // 8 ushorts = 16B
      short8 w = *(const short8*)&tsT[orow * TPITCH + kc];
      *(short8*)&RBt[(size_t)(o0 + orow) * K1 + k0 + kc] = w;
    }
  } else if (bid < TR2_BLKS + PREP_BLKS) {
    const int b = bid - TR2_BLKS;
    const int ri = rel[b];
    if (t < NB)
      attb[b * 32 + t] = tanhf(rel_att[ri * NB + t] * (1.f / EMBR)) * PI_F;
    for (int i = t; i < DIM; i += 256) {
      const float ax = axis[(size_t)b * DIM + i];
      const float ag = argp[(size_t)b * DIM + i];
      Ebf[(size_t)b * D2 + i]       = f2bf(ax);
      Ebf[(size_t)b * D2 + DIM + i] = f2bf(ag);
      const float ra = rel_ax[(size_t)ri * DIM + i];
      const float rg = rel_ar[(size_t)ri * DIM + i];
      h0[(size_t)b * D2 + i] = f2bf(ax + tanhf(ra * (1.f / EMBR)) * PI_F);
      h0[(size_t)b * D2 + DIM + i] =
          f2bf(ag + tanhf(2.f * rg * (1.f / EMBR)) * (PI_F * 0.5f) + PI_F * 0.5f);
    }
  } else {
    // weight cvt: 2 float4 per thread (ILP=2 compensates 2-blk/CU LDS occupancy).
    // All tensor boundaries are multiples of 512 f4 -> one selection per block.
    int i = (bid - TR2_BLKS - PREP_BLKS) * 512 + t;
    const float* s; ushort* d;
    if (i < W1F4) { s = W1; d = W1b; }
    else if ((i -= W1F4) < W2F4) { s = W2; d = W2b; }
    else if ((i -= W2F4) < W0F4) { s = W0; d = W0b; }
    else if ((i -= W0F4) < WA1F4) { s = Wa1; d = Wa1b; }
    else { i -= WA1F4; s = Wa2; d = Wa2b; }
    float4 v0 = ((const float4*)s)[i];
    float4 v1 = ((const float4*)s)[i + 256];
    ushort4 o0, o1;
    o0.x = f2bf(v0.x); o0.y = f2bf(v0.y); o0.z = f2bf(v0.z); o0.w = f2bf(v0.w);
    o1.x = f2bf(v1.x); o1.y = f2bf(v1.y); o1.z = f2bf(v1.z); o1.w = f2bf(v1.w);
    ((ushort4*)d)[i] = o0;
    ((ushort4*)d)[i + 256] = o1;
  }
}

// ======= pipelined NT GEMM: C[m,n] = sum_k A[m,k]*Bt[n,k]; depth-3 prefetch =======
// EPI 1: bf16 out = relu(acc + bias[n]);  EPI 2: fp32 out = acc + bias[n]
template <int EPI>
__global__ __launch_bounds__(256, 2) void gemm_nt(
    const ushort* __restrict__ A, const ushort* __restrict__ Bt,
    const float* __restrict__ bias, float* __restrict__ Cf,
    ushort* __restrict__ Cb, int M, int N, int K) {
  __shared__ ushort As[4][128 * 32];
  __shared__ ushort Bs[4][128 * 32];
  const int tid  = threadIdx.x;
  const int lane = tid & 63, wave = tid >> 6;
  const int wm = wave >> 1, wn = wave & 1;
  const int lrow = lane & 15, quad = lane >> 4;
  const int m0 = blockIdx.y * 128, n0 = blockIdx.x * 128;
  const int T = K >> 5;

  const int rr = lane >> 2;
  const int eo = (lane & 3) * 8;
  const int c1 = wave, c2 = wave + 4;
  const ushort* Ag1 = A  + (size_t)(m0 + c1 * 16 + rr) * K + eo;
  const ushort* Ag2 = A  + (size_t)(m0 + c2 * 16 + rr) * K + eo;
  const ushort* Bg1 = Bt + (size_t)(n0 + c1 * 16 + rr) * K + eo;
  const ushort* Bg2 = Bt + (size_t)(n0 + c2 * 16 + rr) * K + eo;

  auto issue = [&](int slot) {
    const int t  = (slot < T - 1) ? slot : T - 1;
    const int bf = slot & 3;
    const int kk = t << 5;
    gld_lds16(Ag1 + kk, &As[bf][c1 * 512]);
    gld_lds16(Ag2 + kk, &As[bf][c2 * 512]);
    gld_lds16(Bg1 + kk, &Bs[bf][c1 * 512]);
    gld_lds16(Bg2 + kk, &Bs[bf][c2 * 512]);
  };

  f32x4 acc[4][4] = {};
  issue(0); issue(1); issue(2);

  for (int t = 0; t < T; ++t) {
    WAITVM(8);                          // tile t's 4 loads done; 2 batches in flight
    __builtin_amdgcn_s_barrier();
    issue(t + 3);
    const ushort* as = As[t & 3];
    const ushort* bs = Bs[t & 3];
    short8 af[4], bq[4];
#pragma unroll
    for (int i = 0; i < 4; ++i) {
      af[i] = *(const short8*)&as[(wm * 64 + i * 16 + lrow) * 32 + quad * 8];
      bq[i] = *(const short8*)&bs[(wn * 64 + i * 16 + lrow) * 32 + quad * 8];
    }
#pragma unroll
    for (int mi = 0; mi < 4; ++mi)
#pragma unroll
      for (int ni = 0; ni < 4; ++ni)
        acc[mi][ni] = __builtin_amdgcn_mfma_f32_16x16x32_bf16(
            af[mi], bq[ni], acc[mi][ni], 0, 0, 0);
  }
  WAITVM(0);                            // drain clamped prefetches before LDS dealloc

  const int colBase = n0 + wn * 64;
  const int rowBase = m0 + wm * 64;
#pragma unroll
  for (int mi = 0; mi < 4; ++mi) {
#pragma unroll
    for (int ni = 0; ni < 4; ++ni) {
      const int col  = colBase + ni * 16 + lrow;
      const int row0 = rowBase + mi * 16 + quad * 4;
      const float bv = bias[col];
      if (EPI == 1) {
#pragma unroll
        for (int g = 0; g < 4; ++g)
          Cb[(size_t)(row0 + g) * N + col] = f2bf(fmaxf(acc[mi][ni][g] + bv, 0.f));
      } else {
#pragma unroll
        for (int g = 0; g < 4; ++g)
          Cf[(size_t)(row0 + g) * N + col] = acc[mi][ni][g] + bv;
      }
    }
  }
}

// ==== rtrans GEMM v6: i-outer / r-inner, A-resident regs + sched_barrier fences ====
// out[b,o] partial over i-chunk z: sum_r att[b,r] * sum_{i in z} E[b,i]*RB[r,i,o].
// RACE FIX (rule #18 class): raw s_barrier + s_waitcnt builtins are IntrNoMem ->
// plain LDS loads (bq ds_reads) could be software-pipelined ACROSS them by the
// scheduler, reading buffer v%3 before slot v's global_load_lds landed (rt3/4/5
// failures: 0.31/0.37/0.42, run-varying = timing race). sched_barrier(0) after
// each barrier and at each step end pins every step's memory ops inside its
// wait window. af held in VGPRs across all r -> loop LDS reads halve (4xb128).
__global__ __launch_bounds__(256, 2) void gemm_rt6(
    const ushort* __restrict__ E,    // (1024 x 1024) bf16
    const ushort* __restrict__ RBt,  // (1024 x 30720) bf16; row o, col k=r*1024+i
    const float* __restrict__ attb,  // (B, 32)
    float* __restrict__ C1p) {       // (NZ, 1024, 1024) fp32 partials
  __shared__ ushort Bs[3][128 * 32];   // 24 KB ring
  __shared__ ushort As[4][128 * 32];   // 32 KB, staged once (sub-tile ks = k-cols ks*32..+32)
  __shared__ float attL[NB * 128];     // 15 KB, [r][row]
  const int tid  = threadIdx.x;
  const int lane = tid & 63, wave = tid >> 6;
  const int wm = wave >> 1, wn = wave & 1;
  const int lrow = lane & 15, quad = lane >> 4;
  const int n0 = blockIdx.x * 128, m0 = blockIdx.y * 128, z = blockIdx.z;

  const int rr = lane >> 2;
  const int eo = (lane & 3) * 8;

  // --- A stage: 8 gld_lds per wave; sub-tile ks, 64-row half j; 16 rows x 32 cols each ---
#pragma unroll
  for (int j = 0; j < 2; ++j)
#pragma unroll
    for (int ks = 0; ks < 4; ++ks)
      gld_lds16(E + (size_t)(m0 + j * 64 + wave * 16 + rr) * D2 + z * 128 + ks * 32 + eo,
                &As[ks][(j * 64 + wave * 16) * 32]);

  // --- B ring: 2 gld_lds per slot per wave (rows wave*16.. and 64+wave*16..) ---
  const ushort* Bg1 = RBt + (size_t)(n0 + wave * 16 + rr) * K1 + z * 128 + eo;
  const ushort* Bg2 = Bg1 + (size_t)64 * K1;
  auto issue = [&](int slot) {
    const int v  = (slot < 120) ? slot : 119;  // clamp keeps vmcnt bookkeeping exact
    const int bf = slot % 3;
    const size_t ko = (size_t)(v >> 2) * 1024 + (v & 3) * 32;  // r*1024 + ks*32
    gld_lds16(Bg1 + ko, &Bs[bf][(wave * 16) * 32]);
    gld_lds16(Bg2 + ko, &Bs[bf][(64 + wave * 16) * 32]);
  };
  issue(0); issue(1);

  // --- att -> LDS transposed [r][row] (round-0 exact staging pattern) ---
  for (int idx = tid; idx < NB * 128; idx += 256)
    attL[idx] = attb[(size_t)(m0 + (idx & 127)) * 32 + (idx >> 7)];

  __syncthreads();   // FULL drain (vmcnt 0 + lgkm 0) + fence + barrier

  short8 af[4][4];                     // A-fragments, resident across all r
#pragma unroll
  for (int ks = 0; ks < 4; ++ks)
#pragma unroll
    for (int mi = 0; mi < 4; ++mi)
      af[ks][mi] = *(const short8*)&As[ks][(wm * 64 + mi * 16 + lrow) * 32 + quad * 8];

  f32x4 acc[4][4]  = {};
  f32x4 acc2[4][4] = {};

  for (int r = 0; r < NB; ++r) {
#pragma unroll
    for (int ks = 0; ks < 4; ++ks) {
      const int v = r * 4 + ks;
      WAITVM(2);                       // slot v retired (no-op for v<2: pre-drained)
      __builtin_amdgcn_s_barrier();
      SCHED_FENCE();                   // nothing (esp. bq ds_reads) hoists above wait+barrier
      issue(v + 2);                    // writes buf (v+2)%3: != read v%3, != inflight (v+1)%3
      const ushort* bs = Bs[v % 3];
      short8 bq[4];
#pragma unroll
      for (int i = 0; i < 4; ++i)
        bq[i] = *(const short8*)&bs[(wn * 64 + i * 16 + lrow) * 32 + quad * 8];
#pragma unroll
      for (int mi = 0; mi < 4; ++mi)
#pragma unroll
        for (int ni = 0; ni < 4; ++ni)
          acc[mi][ni] = __builtin_amdgcn_mfma_f32_16x16x32_bf16(
              af[ks][mi], bq[ni], acc[mi][ni], 0, 0, 0);
      SCHED_FENCE();                   // nothing sinks out of this step either
    }
    // fold: acc2 += att[row, r] * acc; acc = 0   (round-0 exact scalar pattern)
#pragma unroll
    for (int mi = 0; mi < 4; ++mi)
#pragma unroll
      for (int g = 0; g < 4; ++g) {
        const float s = attL[r * 128 + wm * 64 + mi * 16 + quad * 4 + g];
#pragma unroll
        for (int ni = 0; ni < 4; ++ni) {
          acc2[mi][ni][g] += s * acc[mi][ni][g];
          acc[mi][ni][g] = 0.f;
        }
      }
  }
  WAITVM(0);                           // drain clamped prefetches before LDS dealloc

  float* dst = C1p + (size_t)z * BATCH * D2;
  const int colBase = n0 + wn * 64;
  const int rowBase = m0 + wm * 64;
#pragma unroll
  for (int mi = 0; mi < 4; ++mi)
#pragma unroll
    for (int ni = 0; ni < 4; ++ni) {
      const int col  = colBase + ni * 16 + lrow;
      const int row0 = rowBase + mi * 16 + quad * 4;
#pragma unroll
      for (int g = 0; g < 4; ++g)
        dst[(size_t)(row0 + g) * D2 + col] = acc2[mi][ni][g];
    }
}

// ------- reduce slices + att@rel_bias + LayerNorm -> xrt (fp32), Xb row (bf16) -------
__global__ __launch_bounds__(256) void reduce_ln_rt(
    const float* __restrict__ C1p, const float* __restrict__ att,
    const float* __restrict__ rel_bias, float* __restrict__ xf,
    ushort* __restrict__ Xb) {
  const int b = blockIdx.x, t = threadIdx.x;
  __shared__ float attS[NB];
  __shared__ float sa[4], sb[4];
  if (t < NB) attS[t] = att[b * 32 + t];
  __syncthreads();
  float v[4], sum = 0.f, sq = 0.f;
#pragma unroll
  for (int j = 0; j < 4; ++j) {
    const int o = j * 256 + t;
    float acc = 0.f;
#pragma unroll
    for (int s = 0; s < NZ; ++s)
      acc += C1p[((size_t)s * BATCH + b) * D2 + o];
    float bias = 0.f;
    for (int r = 0; r < NB; ++r) bias += attS[r] * rel_bias[r * D2 + o];
    acc += bias;
    v[j] = acc; sum += acc; sq += acc * acc;
  }
  const int lane = t & 63, wv = t >> 6;
  for (int off = 32; off > 0; off >>= 1) {
    sum += __shfl_down(sum, off, 64);
    sq  += __shfl_down(sq, off, 64);
  }
  if (lane == 0) { sa[wv] = sum; sb[wv] = sq; }
  __syncthreads();
  const float S = sa[0] + sa[1] + sa[2] + sa[3];
  const float Q = sb[0] + sb[1] + sb[2] + sb[3];
  const float mean = S / D2;
  const float inv = rsqrtf(fmaxf(Q / D2 - mean * mean, 0.f) + 1e-5f);
#pragma unroll
  for (int j = 0; j < 4; ++j) {
    const int o = j * 256 + t;
    const float y = (v[j] - mean) * inv;
    xf[(size_t)b * D2 + o] = y;
    Xb[(size_t)b * D2 + o] = f2bf(y);
  }
}

// ---------------- row LayerNorm (mlp branch) ----------------
__global__ __launch_bounds__(256) void ln_rows(
    const float* __restrict__ G, float* __restrict__ xf, ushort* __restrict__ Xb) {
  const int b = blockIdx.x, t = threadIdx.x;
  __shared__ float sa[4], sb[4];
  float v[4], sum = 0.f, sq = 0.f;
#pragma unroll
  for (int j = 0; j < 4; ++j) {
    const int o = j * 256 + t;
    v[j] = G[(size_t)b * D2 + o];
    sum += v[j]; sq += v[j] * v[j];
  }
  const int lane = t & 63, wv = t >> 6;
  for (int off = 32; off > 0; off >>= 1) {
    sum += __shfl_down(sum, off, 64);
    sq  += __shfl_down(sq, off, 64);
  }
  if (lane == 0) { sa[wv] = sum; sb[wv] = sq; }
  __syncthreads();
  const float S = sa[0] + sa[1] + sa[2] + sa[3];
  const float Q = sb[0] + sb[1] + sb[2] + sb[3];
  const float mean = S / D2;
  const float inv = rsqrtf(fmaxf(Q / D2 - mean * mean, 0.f) + 1e-5f);
#pragma unroll
  for (int j = 0; j < 4; ++j) {
    const int o = j * 256 + t;
    const float y = (v[j] - mean) * inv;
    xf[(size_t)b * D2 + o] = y;
    Xb[(size_t)b * D2 + o] = f2bf(y);
  }
}

// -------- softmax over 2 branches + merge + final activations -> out (fp32) --------
__global__ __launch_bounds__(256) void fuse_out(
    const float* __restrict__ L, const float* __restrict__ xrt,
    const float* __restrict__ xml, float* __restrict__ out) {
  const int b = blockIdx.x, t = threadIdx.x;
#pragma unroll
  for (int j = 0; j < 4; ++j) {
    const int o = j * 256 + t;
    const float l0 = L[(size_t)b * D2 + o];
    const float l1 = L[(size_t)(BATCH + b) * D2 + o];
    const float w0 = 1.f / (1.f + expf(l1 - l0));
    const float m = w0 * xrt[(size_t)b * D2 + o] +
                    (1.f - w0) * xml[(size_t)b * D2 + o];
    if (o < DIM)
      out[(size_t)b * DIM + o] = tanhf(m) * PI_F;
    else
      out[(size_t)BATCH * DIM + (size_t)b * DIM + (o - DIM)] =
          tanhf(2.f * m) * (PI_F * 0.5f) + PI_F * 0.5f;
  }
}

extern "C" void kernel_launch(void* const* d_in, const int* in_sizes, int n_in,
                              void* d_out, int out_size, void* d_ws, size_t ws_size,
                              hipStream_t stream) {
  (void)in_sizes; (void)n_in; (void)out_size; (void)ws_size;
  const float* s_axis   = (const float*)d_in[0];
  const float* s_arg    = (const float*)d_in[1];
  const int*   rel      = (const int*)d_in[2];
  const float* rel_base = (const float*)d_in[3];
  const float* rel_att  = (const float*)d_in[4];
  const float* rel_bias = (const float*)d_in[5];
  const float* rel_ax_e = (const float*)d_in[6];
  const float* rel_ar_e = (const float*)d_in[7];
  const float* W1 = (const float*)d_in[8];
  const float* b1 = (const float*)d_in[9];
  const float* W2 = (const float*)d_in[10];
  const float* b2 = (const float*)d_in[11];
  const float* W0 = (const float*)d_in[12];
  const float* b0 = (const float*)d_in[13];
  const float* Wa1 = (const float*)d_in[14];
  const float* ba1 = (const float*)d_in[15];
  const float* Wa2 = (const float*)d_in[16];
  const float* ba2 = (const float*)d_in[17];

  char* ws = (char*)d_ws;
  size_t off = 0;
  ushort* RBt  = (ushort*)(ws + off); off += (size_t)K1 * D2 * 2;            // 63 MB
  float*  C1p  = (float*)(ws + off);  off += (size_t)NZ * BATCH * D2 * 4;    // 33.5 MB
  ushort* Ebf  = (ushort*)(ws + off); off += (size_t)BATCH * D2 * 2;
  ushort* W1b  = (ushort*)(ws + off); off += (size_t)HID * D2 * 2;
  ushort* W2b  = (ushort*)(ws + off); off += (size_t)HID * HID * 2;
  ushort* W0b  = (ushort*)(ws + off); off += (size_t)D2 * HID * 2;
  ushort* Wa1b = (ushort*)(ws + off); off += (size_t)DIM * D2 * 2;
  ushort* Wa2b = (ushort*)(ws + off); off += (size_t)D2 * DIM * 2;
  ushort* h0   = (ushort*)(ws + off); off += (size_t)BATCH * D2 * 2;
  ushort* Xb   = (ushort*)(ws + off); off += (size_t)2 * BATCH * D2 * 2;
  float*  xrt  = (float*)(ws + off);  off += (size_t)BATCH * D2 * 4;
  float*  xml  = (float*)(ws + off);  off += (size_t)BATCH * D2 * 4;
  float*  attb = (float*)(ws + off);  off += (size_t)BATCH * 32 * 4;
  // late buffers alias C1p (dead after reduce_ln_rt); 22 MB <= 33.5 MB
  char* ali = (char*)C1p;
  ushort* H1  = (ushort*)ali; ali += (size_t)BATCH * HID * 2;
  ushort* H2  = (ushort*)ali; ali += (size_t)BATCH * HID * 2;
  float*  G0  = (float*)ali;  ali += (size_t)BATCH * D2 * 4;
  ushort* Aat = (ushort*)ali; ali += (size_t)2 * BATCH * DIM * 2;
  float*  Lg  = (float*)ali;  ali += (size_t)2 * BATCH * D2 * 4;

  mega_prep<<<TR2_BLKS + PREP_BLKS + CVT2_BLKS, 256, 0, stream>>>(
      rel_base, RBt, s_axis, s_arg, rel, rel_att, rel_ax_e, rel_ar_e,
      attb, Ebf, h0, W1, W2, W0, Wa1, Wa2, W1b, W2b, W0b, Wa1b, Wa2b);
  gemm_rt6<<<dim3(D2 / 128, BATCH / 128, NZ), 256, 0, stream>>>(
      Ebf, RBt, attb, C1p);
  reduce_ln_rt<<<BATCH, 256, 0, stream>>>(C1p, attb, rel_bias, xrt, Xb);
  gemm_nt<1><<<dim3(HID / 128, BATCH / 128), 256, 0, stream>>>(
      h0, W1b, b1, nullptr, H1, BATCH, HID, D2);
  gemm_nt<1><<<dim3(HID / 128, BATCH / 128), 256, 0, stream>>>(
      H1, W2b, b2, nullptr, H2, BATCH, HID, HID);
  gemm_nt<2><<<dim3(D2 / 128, BATCH / 128), 256, 0, stream>>>(
      H2, W0b, b0, G0, nullptr, BATCH, D2, HID);
  ln_rows<<<BATCH, 256, 0, stream>>>(G0, xml, Xb + (size_t)BATCH * D2);
  gemm_nt<1><<<dim3(DIM / 128, 2 * BATCH / 128), 256, 0, stream>>>(
      Xb, Wa1b, ba1, nullptr, Aat, 2 * BATCH, DIM, D2);
  gemm_nt<2><<<dim3(D2 / 128, 2 * BATCH / 128), 256, 0, stream>>>(
      Aat, Wa2b, ba2, Lg, nullptr, 2 * BATCH, D2, DIM);
  fuse_out<<<BATCH, 256, 0, stream>>>(Lg, xrt, xml, (float*)d_out);
}

// Round 10
// 398.492 us; speedup vs baseline: 1.0626x; 1.0626x over previous
//
#include <hip/hip_runtime.h>
#include <hip/hip_bf16.h>
#include <stdint.h>

#define PI_F 3.14159265358979f
#define EMBR 0.0275f
#define BATCH 1024
#define DIM 512
#define D2 1024
#define HID 2048
#define NB 30
#define K1 (NB * D2)          // 30720
#define NZ 8                  // i-chunk slices for rtrans GEMM

using short8 = __attribute__((ext_vector_type(8))) short;
using f32x4  = __attribute__((ext_vector_type(4))) float;

// s_waitcnt: vmcnt lo [3:0], expcnt [6:4]=7 (ignore), lgkmcnt [11:8]=0xF (ignore), vmcnt hi [15:14]
#define WAITVM(N) __builtin_amdgcn_s_waitcnt(((N) & 0xF) | (((N) >> 4) << 14) | (0x7 << 4) | (0xF << 8))
#define SCHED_FENCE() __builtin_amdgcn_sched_barrier(0)

__device__ __forceinline__ ushort f2bf(float f) {
  uint32_t u = __builtin_bit_cast(uint32_t, f);
  u += 0x7fffu + ((u >> 16) & 1u);   // RNE
  return (ushort)(u >> 16);
}

// async global->LDS, 16B per lane; LDS dest = wave-uniform base + lane*16
__device__ __forceinline__ void gld_lds16(const void* g, void* l) {
  __builtin_amdgcn_global_load_lds(
      (const __attribute__((address_space(1))) uint32_t*)(uintptr_t)g,
      (__attribute__((address_space(3))) uint32_t*)(uintptr_t)l, 16, 0, 0);
}

// ============ mega prep v2: wide-segment transpose | prep | 2x weight cvts ============
// NOTE (r9 post-mortem): three structurally different transposes all land ~83 us /
// ~2.05 TB/s -> per-CU request-concurrency cap, not segments/occupancy. Keeping v2.
#define TR2_BLKS 960                    // (K1/256=120) x (D2/128=8)
#define PREP_BLKS 1024
#define W1F4 (HID * D2 / 4)             // 524288
#define W2F4 (HID * HID / 4)            // 1048576
#define W0F4 (D2 * HID / 4)             // 524288
#define WA1F4 (DIM * D2 / 4)            // 131072
#define WA2F4 (D2 * DIM / 4)            // 131072
#define CVT2_BLKS ((W1F4 + W2F4 + W0F4 + WA1F4 + WA2F4) / 512)  // 4608 (2 f4/thread)
#define TPITCH 264                      // ushorts; 16B-aligned rows, 128*264*2 = 67584 B

__global__ __launch_bounds__(256) void mega_prep(
    const float* __restrict__ rel_base, ushort* __restrict__ RBt,
    const float* __restrict__ axis, const float* __restrict__ argp,
    const int* __restrict__ rel, const float* __restrict__ rel_att,
    const float* __restrict__ rel_ax, const float* __restrict__ rel_ar,
    float* __restrict__ attb, ushort* __restrict__ Ebf, ushort* __restrict__ h0,
    const float* __restrict__ W1, const float* __restrict__ W2,
    const float* __restrict__ W0, const float* __restrict__ Wa1,
    const float* __restrict__ Wa2,
    ushort* __restrict__ W1b, ushort* __restrict__ W2b, ushort* __restrict__ W0b,
    ushort* __restrict__ Wa1b, ushort* __restrict__ Wa2b) {
  __shared__ ushort tsT[128 * TPITCH];
  const int bid = blockIdx.x, t = threadIdx.x;
  if (bid < TR2_BLKS) {
    // tile k0..k0+255 (src rows) x o0..o0+127 (src cols); RBt[o][k] = bf16(rel_base[k][o])
    const int k0 = (bid >> 3) * 256, o0 = (bid & 7) * 128;
    const int qg  = (t >> 5) * 4;        // k-quad within 32-k pass group
    const int of4 = (t & 31) * 4;        // o offset (4 floats = 16B)
#pragma unroll
    for (int p = 0; p < 8; ++p) {
      const int kq = p * 32 + qg;
      const float* src = &rel_base[(size_t)(k0 + kq) * D2 + o0 + of4];
      float4 v0 = *(const float4*)(src);
      float4 v1 = *(const float4*)(src + D2);
      float4 v2 = *(const float4*)(src + 2 * D2);
      float4 v3 = *(const float4*)(src + 3 * D2);
      ushort4 w;
      w.x = f2bf(v0.x); w.y = f2bf(v1.x); w.z = f2bf(v2.x); w.w = f2bf(v3.x);
      *(ushort4*)&tsT[(of4 + 0) * TPITCH + kq] = w;
      w.x = f2bf(v0.y); w.y = f2bf(v1.y); w.z = f2bf(v2.y); w.w = f2bf(v3.y);
      *(ushort4*)&tsT[(of4 + 1) * TPITCH + kq] = w;
      w.x = f2bf(v0.z); w.y = f2bf(v1.z); w.z = f2bf(v2.z); w.w = f2bf(v3.z);
      *(ushort4*)&tsT[(of4 + 2) * TPITCH + kq] = w;
      w.x = f2bf(v0.w); w.y = f2bf(v1.w); w.z = f2bf(v2.w); w.w = f2bf(v3.w);
      *(ushort4*)&tsT[(of4 + 3) * TPITCH + kq] = w;
    }
    __syncthreads();
#pragma unroll
    for (int p = 0; p < 16; ++p) {
      const int orow = p * 8 + (t >> 5);
      const int kc = (t & 31) * 8;       // 8 ushorts = 16B
      short8 w = *(const short8*)&tsT[orow * TPITCH + kc];
      *(short8*)&RBt[(size_t)(o0 + orow) * K1 + k0 + kc] = w;
    }
  } else if (bid < TR2_BLKS + PREP_BLKS) {
    const int b = bid - TR2_BLKS;
    const int ri = rel[b];
    if (t < NB)
      attb[b * 32 + t] = tanhf(rel_att[ri * NB + t] * (1.f / EMBR)) * PI_F;
    for (int i = t; i < DIM; i += 256) {
      const float ax = axis[(size_t)b * DIM + i];
      const float ag = argp[(size_t)b * DIM + i];
      Ebf[(size_t)b * D2 + i]       = f2bf(ax);
      Ebf[(size_t)b * D2 + DIM + i] = f2bf(ag);
      const float ra = rel_ax[(size_t)ri * DIM + i];
      const float rg = rel_ar[(size_t)ri * DIM + i];
      h0[(size_t)b * D2 + i] = f2bf(ax + tanhf(ra * (1.f / EMBR)) * PI_F);
      h0[(size_t)b * D2 + DIM + i] =
          f2bf(ag + tanhf(2.f * rg * (1.f / EMBR)) * (PI_F * 0.5f) + PI_F * 0.5f);
    }
  } else {
    // weight cvt: 2 float4 per thread; all tensor boundaries are multiples of 512 f4.
    int i = (bid - TR2_BLKS - PREP_BLKS) * 512 + t;
    const float* s; ushort* d;
    if (i < W1F4) { s = W1; d = W1b; }
    else if ((i -= W1F4) < W2F4) { s = W2; d = W2b; }
    else if ((i -= W2F4) < W0F4) { s = W0; d = W0b; }
    else if ((i -= W0F4) < WA1F4) { s = Wa1; d = Wa1b; }
    else { i -= WA1F4; s = Wa2; d = Wa2b; }
    float4 v0 = ((const float4*)s)[i];
    float4 v1 = ((const float4*)s)[i + 256];
    ushort4 o0, o1;
    o0.x = f2bf(v0.x); o0.y = f2bf(v0.y); o0.z = f2bf(v0.z); o0.w = f2bf(v0.w);
    o1.x = f2bf(v1.x); o1.y = f2bf(v1.y); o1.z = f2bf(v1.z); o1.w = f2bf(v1.w);
    ((ushort4*)d)[i] = o0;
    ((ushort4*)d)[i + 256] = o1;
  }
}

// ===== 64x64-tile pipelined NT GEMM: grid-fill variant for the small MLP/attn GEMMs =====
// r9 accounting: the 5 chain GEMMs = ~240us at 64-128 blocks on 256 CUs (half+ GPU idle,
// 1 blk/CU, latency fully exposed). 64x64 tile, 4 waves (wave-tile 32x32), LDS 32KB ->
// 4 blk/CU capacity; grids 2-8x larger. Staging traffic doubles but is L2/L3-resident.
// Same K-order accumulation (numerics identical). SCHED_FENCE race discipline from rt6.
// EPI 1: bf16 out = relu(acc + bias[n]);  EPI 2: fp32 out = acc + bias[n]
template <int EPI>
__global__ __launch_bounds__(256, 4) void gemm_nt64(
    const ushort* __restrict__ A, const ushort* __restrict__ Bt,
    const float* __restrict__ bias, float* __restrict__ Cf,
    ushort* __restrict__ Cb, int M, int N, int K) {
  __shared__ ushort As[4][64 * 32];
  __shared__ ushort Bs[4][64 * 32];
  const int tid  = threadIdx.x;
  const int lane = tid & 63, wave = tid >> 6;
  const int wm = wave >> 1, wn = wave & 1;
  const int lrow = lane & 15, quad = lane >> 4;
  const int m0 = blockIdx.y * 64, n0 = blockIdx.x * 64;
  const int T = K >> 5;

  const int rr = lane >> 2;
  const int eo = (lane & 3) * 8;
  // wave w stages A-chunk w (rows w*16..w*16+15) and B-chunk w: 2 gld_lds per slot.
  const ushort* Ag = A  + (size_t)(m0 + wave * 16 + rr) * K + eo;
  const ushort* Bg = Bt + (size_t)(n0 + wave * 16 + rr) * K + eo;

  auto issue = [&](int slot) {
    const int t  = (slot < T - 1) ? slot : T - 1;   // clamp keeps vmcnt ledger exact
    const int bf = slot & 3;
    const int kk = t << 5;
    gld_lds16(Ag + kk, &As[bf][(wave * 16) * 32]);
    gld_lds16(Bg + kk, &Bs[bf][(wave * 16) * 32]);
  };

  f32x4 acc[2][2] = {};
  issue(0); issue(1); issue(2);

  for (int t = 0; t < T; ++t) {
    WAITVM(4);                          // slot t's 2 loads done; slots t+1,t+2 in flight
    __builtin_amdgcn_s_barrier();
    SCHED_FENCE();                      // no ds_read hoists above wait+barrier (rule #18)
    issue(t + 3);
    const ushort* as = As[t & 3];
    const ushort* bs = Bs[t & 3];
    short8 af[2], bq[2];
#pragma unroll
    for (int i = 0; i < 2; ++i) {
      af[i] = *(const short8*)&as[(wm * 32 + i * 16 + lrow) * 32 + quad * 8];
      bq[i] = *(const short8*)&bs[(wn * 32 + i * 16 + lrow) * 32 + quad * 8];
    }
#pragma unroll
    for (int mi = 0; mi < 2; ++mi)
#pragma unroll
      for (int ni = 0; ni < 2; ++ni)
        acc[mi][ni] = __builtin_amdgcn_mfma_f32_16x16x32_bf16(
            af[mi], bq[ni], acc[mi][ni], 0, 0, 0);
    SCHED_FENCE();                      // nothing sinks out of this step
  }
  WAITVM(0);                            // drain clamped prefetches before LDS dealloc

  const int colBase = n0 + wn * 32;
  const int rowBase = m0 + wm * 32;
#pragma unroll
  for (int mi = 0; mi < 2; ++mi) {
#pragma unroll
    for (int ni = 0; ni < 2; ++ni) {
      const int col  = colBase + ni * 16 + lrow;
      const int row0 = rowBase + mi * 16 + quad * 4;
      const float bv = bias[col];
      if (EPI == 1) {
#pragma unroll
        for (int g = 0; g < 4; ++g)
          Cb[(size_t)(row0 + g) * N + col] = f2bf(fmaxf(acc[mi][ni][g] + bv, 0.f));
      } else {
#pragma unroll
        for (int g = 0; g < 4; ++g)
          Cf[(size_t)(row0 + g) * N + col] = acc[mi][ni][g] + bv;
      }
    }
  }
}

// ==== rtrans GEMM v6: i-outer / r-inner, A-resident regs + sched_barrier fences ====
// ~78us = 825 TF (32% dense peak) -- at the structural ceiling for this class. Frozen.
__global__ __launch_bounds__(256, 2) void gemm_rt6(
    const ushort* __restrict__ E,    // (1024 x 1024) bf16
    const ushort* __restrict__ RBt,  // (1024 x 30720) bf16; row o, col k=r*1024+i
    const float* __restrict__ attb,  // (B, 32)
    float* __restrict__ C1p) {       // (NZ, 1024, 1024) fp32 partials
  __shared__ ushort Bs[3][128 * 32];   // 24 KB ring
  __shared__ ushort As[4][128 * 32];   // 32 KB, staged once (sub-tile ks = k-cols ks*32..+32)
  __shared__ float attL[NB * 128];     // 15 KB, [r][row]
  const int tid  = threadIdx.x;
  const int lane = tid & 63, wave = tid >> 6;
  const int wm = wave >> 1, wn = wave & 1;
  const int lrow = lane & 15, quad = lane >> 4;
  const int n0 = blockIdx.x * 128, m0 = blockIdx.y * 128, z = blockIdx.z;

  const int rr = lane >> 2;
  const int eo = (lane & 3) * 8;

  // --- A stage: 8 gld_lds per wave; sub-tile ks, 64-row half j; 16 rows x 32 cols each ---
#pragma unroll
  for (int j = 0; j < 2; ++j)
#pragma unroll
    for (int ks = 0; ks < 4; ++ks)
      gld_lds16(E + (size_t)(m0 + j * 64 + wave * 16 + rr) * D2 + z * 128 + ks * 32 + eo,
                &As[ks][(j * 64 + wave * 16) * 32]);

  // --- B ring: 2 gld_lds per slot per wave (rows wave*16.. and 64+wave*16..) ---
  const ushort* Bg1 = RBt + (size_t)(n0 + wave * 16 + rr) * K1 + z * 128 + eo;
  const ushort* Bg2 = Bg1 + (size_t)64 * K1;
  auto issue = [&](int slot) {
    const int v  = (slot < 120) ? slot : 119;  // clamp keeps vmcnt bookkeeping exact
    const int bf = slot % 3;
    const size_t ko = (size_t)(v >> 2) * 1024 + (v & 3) * 32;  // r*1024 + ks*32
    gld_lds16(Bg1 + ko, &Bs[bf][(wave * 16) * 32]);
    gld_lds16(Bg2 + ko, &Bs[bf][(64 + wave * 16) * 32]);
  };
  issue(0); issue(1);

  // --- att -> LDS transposed [r][row] ---
  for (int idx = tid; idx < NB * 128; idx += 256)
    attL[idx] = attb[(size_t)(m0 + (idx & 127)) * 32 + (idx >> 7)];

  __syncthreads();   // FULL drain (vmcnt 0 + lgkm 0) + fence + barrier

  short8 af[4][4];                     // A-fragments, resident across all r
#pragma unroll
  for (int ks = 0; ks < 4; ++ks)
#pragma unroll
    for (int mi = 0; mi < 4; ++mi)
      af[ks][mi] = *(const short8*)&As[ks][(wm * 64 + mi * 16 + lrow) * 32 + quad * 8];

  f32x4 acc[4][4]  = {};
  f32x4 acc2[4][4] = {};

  for (int r = 0; r < NB; ++r) {
#pragma unroll
    for (int ks = 0; ks < 4; ++ks) {
      const int v = r * 4 + ks;
      WAITVM(2);                       // slot v retired (no-op for v<2: pre-drained)
      __builtin_amdgcn_s_barrier();
      SCHED_FENCE();                   // nothing (esp. bq ds_reads) hoists above wait+barrier
      issue(v + 2);                    // writes buf (v+2)%3: != read v%3, != inflight (v+1)%3
      const ushort* bs = Bs[v % 3];
      short8 bq[4];
#pragma unroll
      for (int i = 0; i < 4; ++i)
        bq[i] = *(const short8*)&bs[(wn * 64 + i * 16 + lrow) * 32 + quad * 8];
#pragma unroll
      for (int mi = 0; mi < 4; ++mi)
#pragma unroll
        for (int ni = 0; ni < 4; ++ni)
          acc[mi][ni] = __builtin_amdgcn_mfma_f32_16x16x32_bf16(
              af[ks][mi], bq[ni], acc[mi][ni], 0, 0, 0);
      SCHED_FENCE();                   // nothing sinks out of this step either
    }
    // fold: acc2 += att[row, r] * acc; acc = 0
#pragma unroll
    for (int mi = 0; mi < 4; ++mi)
#pragma unroll
      for (int g = 0; g < 4; ++g) {
        const float s = attL[r * 128 + wm * 64 + mi * 16 + quad * 4 + g];
#pragma unroll
        for (int ni = 0; ni < 4; ++ni) {
          acc2[mi][ni][g] += s * acc[mi][ni][g];
          acc[mi][ni][g] = 0.f;
        }
      }
  }
  WAITVM(0);                           // drain clamped prefetches before LDS dealloc

  float* dst = C1p + (size_t)z * BATCH * D2;
  const int colBase = n0 + wn * 64;
  const int rowBase = m0 + wm * 64;
#pragma unroll
  for (int mi = 0; mi < 4; ++mi)
#pragma unroll
    for (int ni = 0; ni < 4; ++ni) {
      const int col  = colBase + ni * 16 + lrow;
      const int row0 = rowBase + mi * 16 + quad * 4;
#pragma unroll
      for (int g = 0; g < 4; ++g)
        dst[(size_t)(row0 + g) * D2 + col] = acc2[mi][ni][g];
    }
}

// ------- reduce slices + att@rel_bias + LayerNorm -> xrt (fp32), Xb row (bf16) -------
__global__ __launch_bounds__(256) void reduce_ln_rt(
    const float* __restrict__ C1p, const float* __restrict__ att,
    const float* __restrict__ rel_bias, float* __restrict__ xf,
    ushort* __restrict__ Xb) {
  const int b = blockIdx.x, t = threadIdx.x;
  __shared__ float attS[NB];
  __shared__ float sa[4], sb[4];
  if (t < NB) attS[t] = att[b * 32 + t];
  __syncthreads();
  float v[4], sum = 0.f, sq = 0.f;
#pragma unroll
  for (int j = 0; j < 4; ++j) {
    const int o = j * 256 + t;
    float acc = 0.f;
#pragma unroll
    for (int s = 0; s < NZ; ++s)
      acc += C1p[((size_t)s * BATCH + b) * D2 + o];
    float bias = 0.f;
    for (int r = 0; r < NB; ++r) bias += attS[r] * rel_bias[r * D2 + o];
    acc += bias;
    v[j] = acc; sum += acc; sq += acc * acc;
  }
  const int lane = t & 63, wv = t >> 6;
  for (int off = 32; off > 0; off >>= 1) {
    sum += __shfl_down(sum, off, 64);
    sq  += __shfl_down(sq, off, 64);
  }
  if (lane == 0) { sa[wv] = sum; sb[wv] = sq; }
  __syncthreads();
  const float S = sa[0] + sa[1] + sa[2] + sa[3];
  const float Q = sb[0] + sb[1] + sb[2] + sb[3];
  const float mean = S / D2;
  const float inv = rsqrtf(fmaxf(Q / D2 - mean * mean, 0.f) + 1e-5f);
#pragma unroll
  for (int j = 0; j < 4; ++j) {
    const int o = j * 256 + t;
    const float y = (v[j] - mean) * inv;
    xf[(size_t)b * D2 + o] = y;
    Xb[(size_t)b * D2 + o] = f2bf(y);
  }
}

// ---------------- row LayerNorm (mlp branch) ----------------
__global__ __launch_bounds__(256) void ln_rows(
    const float* __restrict__ G, float* __restrict__ xf, ushort* __restrict__ Xb) {
  const int b = blockIdx.x, t = threadIdx.x;
  __shared__ float sa[4], sb[4];
  float v[4], sum = 0.f, sq = 0.f;
#pragma unroll
  for (int j = 0; j < 4; ++j) {
    const int o = j * 256 + t;
    v[j] = G[(size_t)b * D2 + o];
    sum += v[j]; sq += v[j] * v[j];
  }
  const int lane = t & 63, wv = t >> 6;
  for (int off = 32; off > 0; off >>= 1) {
    sum += __shfl_down(sum, off, 64);
    sq  += __shfl_down(sq, off, 64);
  }
  if (lane == 0) { sa[wv] = sum; sb[wv] = sq; }
  __syncthreads();
  const float S = sa[0] + sa[1] + sa[2] + sa[3];
  const float Q = sb[0] + sb[1] + sb[2] + sb[3];
  const float mean = S / D2;
  const float inv = rsqrtf(fmaxf(Q / D2 - mean * mean, 0.f) + 1e-5f);
#pragma unroll
  for (int j = 0; j < 4; ++j) {
    const int o = j * 256 + t;
    const float y = (v[j] - mean) * inv;
    xf[(size_t)b * D2 + o] = y;
    Xb[(size_t)b * D2 + o] = f2bf(y);
  }
}

// -------- softmax over 2 branches + merge + final activations -> out (fp32) --------
__global__ __launch_bounds__(256) void fuse_out(
    const float* __restrict__ L, const float* __restrict__ xrt,
    const float* __restrict__ xml, float* __restrict__ out) {
  const int b = blockIdx.x, t = threadIdx.x;
#pragma unroll
  for (int j = 0; j < 4; ++j) {
    const int o = j * 256 + t;
    const float l0 = L[(size_t)b * D2 + o];
    const float l1 = L[(size_t)(BATCH + b) * D2 + o];
    const float w0 = 1.f / (1.f + expf(l1 - l0));
    const float m = w0 * xrt[(size_t)b * D2 + o] +
                    (1.f - w0) * xml[(size_t)b * D2 + o];
    if (o < DIM)
      out[(size_t)b * DIM + o] = tanhf(m) * PI_F;
    else
      out[(size_t)BATCH * DIM + (size_t)b * DIM + (o - DIM)] =
          tanhf(2.f * m) * (PI_F * 0.5f) + PI_F * 0.5f;
  }
}

extern "C" void kernel_launch(void* const* d_in, const int* in_sizes, int n_in,
                              void* d_out, int out_size, void* d_ws, size_t ws_size,
                              hipStream_t stream) {
  (void)in_sizes; (void)n_in; (void)out_size; (void)ws_size;
  const float* s_axis   = (const float*)d_in[0];
  const float* s_arg    = (const float*)d_in[1];
  const int*   rel      = (const int*)d_in[2];
  const float* rel_base = (const float*)d_in[3];
  const float* rel_att  = (const float*)d_in[4];
  const float* rel_bias = (const float*)d_in[5];
  const float* rel_ax_e = (const float*)d_in[6];
  const float* rel_ar_e = (const float*)d_in[7];
  const float* W1 = (const float*)d_in[8];
  const float* b1 = (const float*)d_in[9];
  const float* W2 = (const float*)d_in[10];
  const float* b2 = (const float*)d_in[11];
  const float* W0 = (const float*)d_in[12];
  const float* b0 = (const float*)d_in[13];
  const float* Wa1 = (const float*)d_in[14];
  const float* ba1 = (const float*)d_in[15];
  const float* Wa2 = (const float*)d_in[16];
  const float* ba2 = (const float*)d_in[17];

  char* ws = (char*)d_ws;
  size_t off = 0;
  ushort* RBt  = (ushort*)(ws + off); off += (size_t)K1 * D2 * 2;            // 63 MB
  float*  C1p  = (float*)(ws + off);  off += (size_t)NZ * BATCH * D2 * 4;    // 33.5 MB
  ushort* Ebf  = (ushort*)(ws + off); off += (size_t)BATCH * D2 * 2;
  ushort* W1b  = (ushort*)(ws + off); off += (size_t)HID * D2 * 2;
  ushort* W2b  = (ushort*)(ws + off); off += (size_t)HID * HID * 2;
  ushort* W0b  = (ushort*)(ws + off); off += (size_t)D2 * HID * 2;
  ushort* Wa1b = (ushort*)(ws + off); off += (size_t)DIM * D2 * 2;
  ushort* Wa2b = (ushort*)(ws + off); off += (size_t)D2 * DIM * 2;
  ushort* h0   = (ushort*)(ws + off); off += (size_t)BATCH * D2 * 2;
  ushort* Xb   = (ushort*)(ws + off); off += (size_t)2 * BATCH * D2 * 2;
  float*  xrt  = (float*)(ws + off);  off += (size_t)BATCH * D2 * 4;
  float*  xml  = (float*)(ws + off);  off += (size_t)BATCH * D2 * 4;
  float*  attb = (float*)(ws + off);  off += (size_t)BATCH * 32 * 4;
  // late buffers alias C1p (dead after reduce_ln_rt); 22 MB <= 33.5 MB
  char* ali = (char*)C1p;
  ushort* H1  = (ushort*)ali; ali += (size_t)BATCH * HID * 2;
  ushort* H2  = (ushort*)ali; ali += (size_t)BATCH * HID * 2;
  float*  G0  = (float*)ali;  ali += (size_t)BATCH * D2 * 4;
  ushort* Aat = (ushort*)ali; ali += (size_t)2 * BATCH * DIM * 2;
  float*  Lg  = (float*)ali;  ali += (size_t)2 * BATCH * D2 * 4;

  mega_prep<<<TR2_BLKS + PREP_BLKS + CVT2_BLKS, 256, 0, stream>>>(
      rel_base, RBt, s_axis, s_arg, rel, rel_att, rel_ax_e, rel_ar_e,
      attb, Ebf, h0, W1, W2, W0, Wa1, Wa2, W1b, W2b, W0b, Wa1b, Wa2b);
  gemm_rt6<<<dim3(D2 / 128, BATCH / 128, NZ), 256, 0, stream>>>(
      Ebf, RBt, attb, C1p);
  reduce_ln_rt<<<BATCH, 256, 0, stream>>>(C1p, attb, rel_bias, xrt, Xb);
  gemm_nt64<1><<<dim3(HID / 64, BATCH / 64), 256, 0, stream>>>(
      h0, W1b, b1, nullptr, H1, BATCH, HID, D2);
  gemm_nt64<1><<<dim3(HID / 64, BATCH / 64), 256, 0, stream>>>(
      H1, W2b, b2, nullptr, H2, BATCH, HID, HID);
  gemm_nt64<2><<<dim3(D2 / 64, BATCH / 64), 256, 0, stream>>>(
      H2, W0b, b0, G0, nullptr, BATCH, D2, HID);
  ln_rows<<<BATCH, 256, 0, stream>>>(G0, xml, Xb + (size_t)BATCH * D2);
  gemm_nt64<1><<<dim3(DIM / 64, 2 * BATCH / 64), 256, 0, stream>>>(
      Xb, Wa1b, ba1, nullptr, Aat, 2 * BATCH, DIM, D2);
  gemm_nt64<2><<<dim3(D2 / 64, 2 * BATCH / 64), 256, 0, stream>>>(
      Aat, Wa2b, ba2, Lg, nullptr, 2 * BATCH, D2, DIM);
  fuse_out<<<BATCH, 256, 0, stream>>>(Lg, xrt, xml, (float*)d_out);
}

// Round 11
// 388.053 us; speedup vs baseline: 1.0911x; 1.0269x over previous
//
#include <hip/hip_runtime.h>
#include <hip/hip_bf16.h>
#include <stdint.h>

#define PI_F 3.14159265358979f
#define EMBR 0.0275f
#define BATCH 1024
#define DIM 512
#define D2 1024
#define HID 2048
#define NB 30
#define K1 (NB * D2)          // 30720
#define NZ 8                  // i-chunk slices for rtrans GEMM

using short8 = __attribute__((ext_vector_type(8))) short;
using f32x4  = __attribute__((ext_vector_type(4))) float;

// s_waitcnt: vmcnt lo [3:0], expcnt [6:4]=7 (ignore), lgkmcnt [11:8]=0xF (ignore), vmcnt hi [15:14]
#define WAITVM(N) __builtin_amdgcn_s_waitcnt(((N) & 0xF) | (((N) >> 4) << 14) | (0x7 << 4) | (0xF << 8))
#define SCHED_FENCE() __builtin_amdgcn_sched_barrier(0)

__device__ __forceinline__ ushort f2bf(float f) {
  uint32_t u = __builtin_bit_cast(uint32_t, f);
  u += 0x7fffu + ((u >> 16) & 1u);   // RNE
  return (ushort)(u >> 16);
}

// async global->LDS, 16B per lane; LDS dest = wave-uniform base + lane*16
__device__ __forceinline__ void gld_lds16(const void* g, void* l) {
  __builtin_amdgcn_global_load_lds(
      (const __attribute__((address_space(1))) uint32_t*)(uintptr_t)g,
      (__attribute__((address_space(3))) uint32_t*)(uintptr_t)l, 16, 0, 0);
}

// ============ mega prep v2: wide-segment transpose | prep | 2x weight cvts ============
// NOTE (r9/r10): three structurally different transposes all land ~83-86 us /
// ~2.0 TB/s -> per-CU request-concurrency cap, not segments/occupancy. Frozen.
#define TR2_BLKS 960                    // (K1/256=120) x (D2/128=8)
#define PREP_BLKS 1024
#define W1F4 (HID * D2 / 4)             // 524288
#define W2F4 (HID * HID / 4)            // 1048576
#define W0F4 (D2 * HID / 4)             // 524288
#define WA1F4 (DIM * D2 / 4)            // 131072
#define WA2F4 (D2 * DIM / 4)            // 131072
#define CVT2_BLKS ((W1F4 + W2F4 + W0F4 + WA1F4 + WA2F4) / 512)  // 4608 (2 f4/thread)
#define TPITCH 264                      // ushorts; 16B-aligned rows, 128*264*2 = 67584 B

__global__ __launch_bounds__(256) void mega_prep(
    const float* __restrict__ rel_base, ushort* __restrict__ RBt,
    const float* __restrict__ axis, const float* __restrict__ argp,
    const int* __restrict__ rel, const float* __restrict__ rel_att,
    const float* __restrict__ rel_ax, const float* __restrict__ rel_ar,
    float* __restrict__ attb, ushort* __restrict__ Ebf, ushort* __restrict__ h0,
    const float* __restrict__ W1, const float* __restrict__ W2,
    const float* __restrict__ W0, const float* __restrict__ Wa1,
    const float* __restrict__ Wa2,
    ushort* __restrict__ W1b, ushort* __restrict__ W2b, ushort* __restrict__ W0b,
    ushort* __restrict__ Wa1b, ushort* __restrict__ Wa2b) {
  __shared__ ushort tsT[128 * TPITCH];
  const int bid = blockIdx.x, t = threadIdx.x;
  if (bid < TR2_BLKS) {
    // tile k0..k0+255 (src rows) x o0..o0+127 (src cols); RBt[o][k] = bf16(rel_base[k][o])
    const int k0 = (bid >> 3) * 256, o0 = (bid & 7) * 128;
    const int qg  = (t >> 5) * 4;        // k-quad within 32-k pass group
    const int of4 = (t & 31) * 4;        // o offset (4 floats = 16B)
#pragma unroll
    for (int p = 0; p < 8; ++p) {
      const int kq = p * 32 + qg;
      const float* src = &rel_base[(size_t)(k0 + kq) * D2 + o0 + of4];
      float4 v0 = *(const float4*)(src);
      float4 v1 = *(const float4*)(src + D2);
      float4 v2 = *(const float4*)(src + 2 * D2);
      float4 v3 = *(const float4*)(src + 3 * D2);
      ushort4 w;
      w.x = f2bf(v0.x); w.y = f2bf(v1.x); w.z = f2bf(v2.x); w.w = f2bf(v3.x);
      *(ushort4*)&tsT[(of4 + 0) * TPITCH + kq] = w;
      w.x = f2bf(v0.y); w.y = f2bf(v1.y); w.z = f2bf(v2.y); w.w = f2bf(v3.y);
      *(ushort4*)&tsT[(of4 + 1) * TPITCH + kq] = w;
      w.x = f2bf(v0.z); w.y = f2bf(v1.z); w.z = f2bf(v2.z); w.w = f2bf(v3.z);
      *(ushort4*)&tsT[(of4 + 2) * TPITCH + kq] = w;
      w.x = f2bf(v0.w); w.y = f2bf(v1.w); w.z = f2bf(v2.w); w.w = f2bf(v3.w);
      *(ushort4*)&tsT[(of4 + 3) * TPITCH + kq] = w;
    }
    __syncthreads();
#pragma unroll
    for (int p = 0; p < 16; ++p) {
      const int orow = p * 8 + (t >> 5);
      const int kc = (t & 31) * 8;       // 8 ushorts = 16B
      short8 w = *(const short8*)&tsT[orow * TPITCH + kc];
      *(short8*)&RBt[(size_t)(o0 + orow) * K1 + k0 + kc] = w;
    }
  } else if (bid < TR2_BLKS + PREP_BLKS) {
    const int b = bid - TR2_BLKS;
    const int ri = rel[b];
    if (t < NB)
      attb[b * 32 + t] = tanhf(rel_att[ri * NB + t] * (1.f / EMBR)) * PI_F;
    for (int i = t; i < DIM; i += 256) {
      const float ax = axis[(size_t)b * DIM + i];
      const float ag = argp[(size_t)b * DIM + i];
      Ebf[(size_t)b * D2 + i]       = f2bf(ax);
      Ebf[(size_t)b * D2 + DIM + i] = f2bf(ag);
      const float ra = rel_ax[(size_t)ri * DIM + i];
      const float rg = rel_ar[(size_t)ri * DIM + i];
      h0[(size_t)b * D2 + i] = f2bf(ax + tanhf(ra * (1.f / EMBR)) * PI_F);
      h0[(size_t)b * D2 + DIM + i] =
          f2bf(ag + tanhf(2.f * rg * (1.f / EMBR)) * (PI_F * 0.5f) + PI_F * 0.5f);
    }
  } else {
    // weight cvt: 2 float4 per thread; all tensor boundaries are multiples of 512 f4.
    int i = (bid - TR2_BLKS - PREP_BLKS) * 512 + t;
    const float* s; ushort* d;
    if (i < W1F4) { s = W1; d = W1b; }
    else if ((i -= W1F4) < W2F4) { s = W2; d = W2b; }
    else if ((i -= W2F4) < W0F4) { s = W0; d = W0b; }
    else if ((i -= W0F4) < WA1F4) { s = Wa1; d = Wa1b; }
    else { i -= WA1F4; s = Wa2; d = Wa2b; }
    float4 v0 = ((const float4*)s)[i];
    float4 v1 = ((const float4*)s)[i + 256];
    ushort4 o0, o1;
    o0.x = f2bf(v0.x); o0.y = f2bf(v0.y); o0.z = f2bf(v0.z); o0.w = f2bf(v0.w);
    o1.x = f2bf(v1.x); o1.y = f2bf(v1.y); o1.z = f2bf(v1.z); o1.w = f2bf(v1.w);
    ((ushort4*)d)[i] = o0;
    ((ushort4*)d)[i + 256] = o1;
  }
}

// ===== 64x64-tile, K-step-64 NT GEMM: work-per-barrier x2 vs nt64 (r10 post-mortem) =====
// r10: nt64 only gained 25us -> chain is per-STEP latency-bound (barrier spread + L2/L3
// fragment latency ~600+cy dominates a 4-MFMA step). Fix: 2 k-sub-tiles per barrier
// window (8 MFMA/wave/step, T halves), 3-buf ring depth-2, LDS 48KB -> 3 blk/CU.
// Same K-ascending accumulation; rt6-proven SCHED_FENCE + vmcnt-ledger discipline.
// EPI 1: bf16 out = relu(acc + bias[n]);  EPI 2: fp32 out = acc + bias[n]
template <int EPI>
__global__ __launch_bounds__(256, 3) void gemm_ntk64(
    const ushort* __restrict__ A, const ushort* __restrict__ Bt,
    const float* __restrict__ bias, float* __restrict__ Cf,
    ushort* __restrict__ Cb, int M, int N, int K) {
  __shared__ ushort As[3][2][64 * 32];   // 3 bufs x 2 k-subs x 4KB = 24KB
  __shared__ ushort Bs[3][2][64 * 32];   // 24KB
  const int tid  = threadIdx.x;
  const int lane = tid & 63, wave = tid >> 6;
  const int wm = wave >> 1, wn = wave & 1;
  const int lrow = lane & 15, quad = lane >> 4;
  const int m0 = blockIdx.y * 64, n0 = blockIdx.x * 64;
  const int T = K >> 6;                  // K-step = 64

  const int rr = lane >> 2;
  const int eo = (lane & 3) * 8;
  // wave w stages its 16-row chunk of A and B: 4 gld_lds per slot (2 subs x 2 ops).
  const ushort* Ag = A  + (size_t)(m0 + wave * 16 + rr) * K + eo;
  const ushort* Bg = Bt + (size_t)(n0 + wave * 16 + rr) * K + eo;

  auto issue = [&](int slot) {
    const int v  = (slot < T - 1) ? slot : T - 1;   // clamp keeps vmcnt ledger exact
    const int bf = slot % 3;
    const int kk = v << 6;
    gld_lds16(Ag + kk,      &As[bf][0][(wave * 16) * 32]);
    gld_lds16(Ag + kk + 32, &As[bf][1][(wave * 16) * 32]);
    gld_lds16(Bg + kk,      &Bs[bf][0][(wave * 16) * 32]);
    gld_lds16(Bg + kk + 32, &Bs[bf][1][(wave * 16) * 32]);
  };

  f32x4 acc[2][2] = {};
  issue(0); issue(1);                   // 8 outstanding

  for (int t = 0; t < T; ++t) {
    WAITVM(4);                          // slot t's 4 loads done; slot t+1 in flight
    __builtin_amdgcn_s_barrier();
    SCHED_FENCE();                      // no ds_read hoists above wait+barrier (rule #18)
    issue(t + 2);                       // write buf (t+2)%3: != read t%3, != inflight (t+1)%3
    const int bf = t % 3;
    short8 af[2][2], bq[2][2];
#pragma unroll
    for (int s = 0; s < 2; ++s)
#pragma unroll
      for (int i = 0; i < 2; ++i) {
        af[s][i] = *(const short8*)&As[bf][s][(wm * 32 + i * 16 + lrow) * 32 + quad * 8];
        bq[s][i] = *(const short8*)&Bs[bf][s][(wn * 32 + i * 16 + lrow) * 32 + quad * 8];
      }
#pragma unroll
    for (int s = 0; s < 2; ++s)         // k ascending: sub 0 then sub 1 (numerics preserved)
#pragma unroll
      for (int mi = 0; mi < 2; ++mi)
#pragma unroll
        for (int ni = 0; ni < 2; ++ni)
          acc[mi][ni] = __builtin_amdgcn_mfma_f32_16x16x32_bf16(
              af[s][mi], bq[s][ni], acc[mi][ni], 0, 0, 0);
    SCHED_FENCE();                      // nothing sinks out of this step
  }
  WAITVM(0);                            // drain clamped prefetches before LDS dealloc

  const int colBase = n0 + wn * 32;
  const int rowBase = m0 + wm * 32;
#pragma unroll
  for (int mi = 0; mi < 2; ++mi) {
#pragma unroll
    for (int ni = 0; ni < 2; ++ni) {
      const int col  = colBase + ni * 16 + lrow;
      const int row0 = rowBase + mi * 16 + quad * 4;
      const float bv = bias[col];
      if (EPI == 1) {
#pragma unroll
        for (int g = 0; g < 4; ++g)
          Cb[(size_t)(row0 + g) * N + col] = f2bf(fmaxf(acc[mi][ni][g] + bv, 0.f));
      } else {
#pragma unroll
        for (int g = 0; g < 4; ++g)
          Cf[(size_t)(row0 + g) * N + col] = acc[mi][ni][g] + bv;
      }
    }
  }
}

// ==== rtrans GEMM v6: i-outer / r-inner, A-resident regs + sched_barrier fences ====
// <85us = ~760+ TF -- near the structural ceiling for this class. Frozen.
__global__ __launch_bounds__(256, 2) void gemm_rt6(
    const ushort* __restrict__ E,    // (1024 x 1024) bf16
    const ushort* __restrict__ RBt,  // (1024 x 30720) bf16; row o, col k=r*1024+i
    const float* __restrict__ attb,  // (B, 32)
    float* __restrict__ C1p) {       // (NZ, 1024, 1024) fp32 partials
  __shared__ ushort Bs[3][128 * 32];   // 24 KB ring
  __shared__ ushort As[4][128 * 32];   // 32 KB, staged once (sub-tile ks = k-cols ks*32..+32)
  __shared__ float attL[NB * 128];     // 15 KB, [r][row]
  const int tid  = threadIdx.x;
  const int lane = tid & 63, wave = tid >> 6;
  const int wm = wave >> 1, wn = wave & 1;
  const int lrow = lane & 15, quad = lane >> 4;
  const int n0 = blockIdx.x * 128, m0 = blockIdx.y * 128, z = blockIdx.z;

  const int rr = lane >> 2;
  const int eo = (lane & 3) * 8;

  // --- A stage: 8 gld_lds per wave; sub-tile ks, 64-row half j; 16 rows x 32 cols each ---
#pragma unroll
  for (int j = 0; j < 2; ++j)
#pragma unroll
    for (int ks = 0; ks < 4; ++ks)
      gld_lds16(E + (size_t)(m0 + j * 64 + wave * 16 + rr) * D2 + z * 128 + ks * 32 + eo,
                &As[ks][(j * 64 + wave * 16) * 32]);

  // --- B ring: 2 gld_lds per slot per wave (rows wave*16.. and 64+wave*16..) ---
  const ushort* Bg1 = RBt + (size_t)(n0 + wave * 16 + rr) * K1 + z * 128 + eo;
  const ushort* Bg2 = Bg1 + (size_t)64 * K1;
  auto issue = [&](int slot) {
    const int v  = (slot < 120) ? slot : 119;  // clamp keeps vmcnt bookkeeping exact
    const int bf = slot % 3;
    const size_t ko = (size_t)(v >> 2) * 1024 + (v & 3) * 32;  // r*1024 + ks*32
    gld_lds16(Bg1 + ko, &Bs[bf][(wave * 16) * 32]);
    gld_lds16(Bg2 + ko, &Bs[bf][(64 + wave * 16) * 32]);
  };
  issue(0); issue(1);

  // --- att -> LDS transposed [r][row] ---
  for (int idx = tid; idx < NB * 128; idx += 256)
    attL[idx] = attb[(size_t)(m0 + (idx & 127)) * 32 + (idx >> 7)];

  __syncthreads();   // FULL drain (vmcnt 0 + lgkm 0) + fence + barrier

  short8 af[4][4];                     // A-fragments, resident across all r
#pragma unroll
  for (int ks = 0; ks < 4; ++ks)
#pragma unroll
    for (int mi = 0; mi < 4; ++mi)
      af[ks][mi] = *(const short8*)&As[ks][(wm * 64 + mi * 16 + lrow) * 32 + quad * 8];

  f32x4 acc[4][4]  = {};
  f32x4 acc2[4][4] = {};

  for (int r = 0; r < NB; ++r) {
#pragma unroll
    for (int ks = 0; ks < 4; ++ks) {
      const int v = r * 4 + ks;
      WAITVM(2);                       // slot v retired (no-op for v<2: pre-drained)
      __builtin_amdgcn_s_barrier();
      SCHED_FENCE();                   // nothing (esp. bq ds_reads) hoists above wait+barrier
      issue(v + 2);                    // writes buf (v+2)%3: != read v%3, != inflight (v+1)%3
      const ushort* bs = Bs[v % 3];
      short8 bq[4];
#pragma unroll
      for (int i = 0; i < 4; ++i)
        bq[i] = *(const short8*)&bs[(wn * 64 + i * 16 + lrow) * 32 + quad * 8];
#pragma unroll
      for (int mi = 0; mi < 4; ++mi)
#pragma unroll
        for (int ni = 0; ni < 4; ++ni)
          acc[mi][ni] = __builtin_amdgcn_mfma_f32_16x16x32_bf16(
              af[ks][mi], bq[ni], acc[mi][ni], 0, 0, 0);
      SCHED_FENCE();                   // nothing sinks out of this step either
    }
    // fold: acc2 += att[row, r] * acc; acc = 0
#pragma unroll
    for (int mi = 0; mi < 4; ++mi)
#pragma unroll
      for (int g = 0; g < 4; ++g) {
        const float s = attL[r * 128 + wm * 64 + mi * 16 + quad * 4 + g];
#pragma unroll
        for (int ni = 0; ni < 4; ++ni) {
          acc2[mi][ni][g] += s * acc[mi][ni][g];
          acc[mi][ni][g] = 0.f;
        }
      }
  }
  WAITVM(0);                           // drain clamped prefetches before LDS dealloc

  float* dst = C1p + (size_t)z * BATCH * D2;
  const int colBase = n0 + wn * 64;
  const int rowBase = m0 + wm * 64;
#pragma unroll
  for (int mi = 0; mi < 4; ++mi)
#pragma unroll
    for (int ni = 0; ni < 4; ++ni) {
      const int col  = colBase + ni * 16 + lrow;
      const int row0 = rowBase + mi * 16 + quad * 4;
#pragma unroll
      for (int g = 0; g < 4; ++g)
        dst[(size_t)(row0 + g) * D2 + col] = acc2[mi][ni][g];
    }
}

// ------- reduce slices + att@rel_bias + LayerNorm -> xrt (fp32), Xb row (bf16) -------
__global__ __launch_bounds__(256) void reduce_ln_rt(
    const float* __restrict__ C1p, const float* __restrict__ att,
    const float* __restrict__ rel_bias, float* __restrict__ xf,
    ushort* __restrict__ Xb) {
  const int b = blockIdx.x, t = threadIdx.x;
  __shared__ float attS[NB];
  __shared__ float sa[4], sb[4];
  if (t < NB) attS[t] = att[b * 32 + t];
  __syncthreads();
  float v[4], sum = 0.f, sq = 0.f;
#pragma unroll
  for (int j = 0; j < 4; ++j) {
    const int o = j * 256 + t;
    float acc = 0.f;
#pragma unroll
    for (int s = 0; s < NZ; ++s)
      acc += C1p[((size_t)s * BATCH + b) * D2 + o];
    float bias = 0.f;
    for (int r = 0; r < NB; ++r) bias += attS[r] * rel_bias[r * D2 + o];
    acc += bias;
    v[j] = acc; sum += acc; sq += acc * acc;
  }
  const int lane = t & 63, wv = t >> 6;
  for (int off = 32; off > 0; off >>= 1) {
    sum += __shfl_down(sum, off, 64);
    sq  += __shfl_down(sq, off, 64);
  }
  if (lane == 0) { sa[wv] = sum; sb[wv] = sq; }
  __syncthreads();
  const float S = sa[0] + sa[1] + sa[2] + sa[3];
  const float Q = sb[0] + sb[1] + sb[2] + sb[3];
  const float mean = S / D2;
  const float inv = rsqrtf(fmaxf(Q / D2 - mean * mean, 0.f) + 1e-5f);
#pragma unroll
  for (int j = 0; j < 4; ++j) {
    const int o = j * 256 + t;
    const float y = (v[j] - mean) * inv;
    xf[(size_t)b * D2 + o] = y;
    Xb[(size_t)b * D2 + o] = f2bf(y);
  }
}

// ---------------- row LayerNorm (mlp branch) ----------------
__global__ __launch_bounds__(256) void ln_rows(
    const float* __restrict__ G, float* __restrict__ xf, ushort* __restrict__ Xb) {
  const int b = blockIdx.x, t = threadIdx.x;
  __shared__ float sa[4], sb[4];
  float v[4], sum = 0.f, sq = 0.f;
#pragma unroll
  for (int j = 0; j < 4; ++j) {
    const int o = j * 256 + t;
    v[j] = G[(size_t)b * D2 + o];
    sum += v[j]; sq += v[j] * v[j];
  }
  const int lane = t & 63, wv = t >> 6;
  for (int off = 32; off > 0; off >>= 1) {
    sum += __shfl_down(sum, off, 64);
    sq  += __shfl_down(sq, off, 64);
  }
  if (lane == 0) { sa[wv] = sum; sb[wv] = sq; }
  __syncthreads();
  const float S = sa[0] + sa[1] + sa[2] + sa[3];
  const float Q = sb[0] + sb[1] + sb[2] + sb[3];
  const float mean = S / D2;
  const float inv = rsqrtf(fmaxf(Q / D2 - mean * mean, 0.f) + 1e-5f);
#pragma unroll
  for (int j = 0; j < 4; ++j) {
    const int o = j * 256 + t;
    const float y = (v[j] - mean) * inv;
    xf[(size_t)b * D2 + o] = y;
    Xb[(size_t)b * D2 + o] = f2bf(y);
  }
}

// -------- softmax over 2 branches + merge + final activations -> out (fp32) --------
__global__ __launch_bounds__(256) void fuse_out(
    const float* __restrict__ L, const float* __restrict__ xrt,
    const float* __restrict__ xml, float* __restrict__ out) {
  const int b = blockIdx.x, t = threadIdx.x;
#pragma unroll
  for (int j = 0; j < 4; ++j) {
    const int o = j * 256 + t;
    const float l0 = L[(size_t)b * D2 + o];
    const float l1 = L[(size_t)(BATCH + b) * D2 + o];
    const float w0 = 1.f / (1.f + expf(l1 - l0));
    const float m = w0 * xrt[(size_t)b * D2 + o] +
                    (1.f - w0) * xml[(size_t)b * D2 + o];
    if (o < DIM)
      out[(size_t)b * DIM + o] = tanhf(m) * PI_F;
    else
      out[(size_t)BATCH * DIM + (size_t)b * DIM + (o - DIM)] =
          tanhf(2.f * m) * (PI_F * 0.5f) + PI_F * 0.5f;
  }
}

extern "C" void kernel_launch(void* const* d_in, const int* in_sizes, int n_in,
                              void* d_out, int out_size, void* d_ws, size_t ws_size,
                              hipStream_t stream) {
  (void)in_sizes; (void)n_in; (void)out_size; (void)ws_size;
  const float* s_axis   = (const float*)d_in[0];
  const float* s_arg    = (const float*)d_in[1];
  const int*   rel      = (const int*)d_in[2];
  const float* rel_base = (const float*)d_in[3];
  const float* rel_att  = (const float*)d_in[4];
  const float* rel_bias = (const float*)d_in[5];
  const float* rel_ax_e = (const float*)d_in[6];
  const float* rel_ar_e = (const float*)d_in[7];
  const float* W1 = (const float*)d_in[8];
  const float* b1 = (const float*)d_in[9];
  const float* W2 = (const float*)d_in[10];
  const float* b2 = (const float*)d_in[11];
  const float* W0 = (const float*)d_in[12];
  const float* b0 = (const float*)d_in[13];
  const float* Wa1 = (const float*)d_in[14];
  const float* ba1 = (const float*)d_in[15];
  const float* Wa2 = (const float*)d_in[16];
  const float* ba2 = (const float*)d_in[17];

  char* ws = (char*)d_ws;
  size_t off = 0;
  ushort* RBt  = (ushort*)(ws + off); off += (size_t)K1 * D2 * 2;            // 63 MB
  float*  C1p  = (float*)(ws + off);  off += (size_t)NZ * BATCH * D2 * 4;    // 33.5 MB
  ushort* Ebf  = (ushort*)(ws + off); off += (size_t)BATCH * D2 * 2;
  ushort* W1b  = (ushort*)(ws + off); off += (size_t)HID * D2 * 2;
  ushort* W2b  = (ushort*)(ws + off); off += (size_t)HID * HID * 2;
  ushort* W0b  = (ushort*)(ws + off); off += (size_t)D2 * HID * 2;
  ushort* Wa1b = (ushort*)(ws + off); off += (size_t)DIM * D2 * 2;
  ushort* Wa2b = (ushort*)(ws + off); off += (size_t)D2 * DIM * 2;
  ushort* h0   = (ushort*)(ws + off); off += (size_t)BATCH * D2 * 2;
  ushort* Xb   = (ushort*)(ws + off); off += (size_t)2 * BATCH * D2 * 2;
  float*  xrt  = (float*)(ws + off);  off += (size_t)BATCH * D2 * 4;
  float*  xml  = (float*)(ws + off);  off += (size_t)BATCH * D2 * 4;
  float*  attb = (float*)(ws + off);  off += (size_t)BATCH * 32 * 4;
  // late buffers alias C1p (dead after reduce_ln_rt); 22 MB <= 33.5 MB
  char* ali = (char*)C1p;
  ushort* H1  = (ushort*)ali; ali += (size_t)BATCH * HID * 2;
  ushort* H2  = (ushort*)ali; ali += (size_t)BATCH * HID * 2;
  float*  G0  = (float*)ali;  ali += (size_t)BATCH * D2 * 4;
  ushort* Aat = (ushort*)ali; ali += (size_t)2 * BATCH * DIM * 2;
  float*  Lg  = (float*)ali;  ali += (size_t)2 * BATCH * D2 * 4;

  mega_prep<<<TR2_BLKS + PREP_BLKS + CVT2_BLKS, 256, 0, stream>>>(
      rel_base, RBt, s_axis, s_arg, rel, rel_att, rel_ax_e, rel_ar_e,
      attb, Ebf, h0, W1, W2, W0, Wa1, Wa2, W1b, W2b, W0b, Wa1b, Wa2b);
  gemm_rt6<<<dim3(D2 / 128, BATCH / 128, NZ), 256, 0, stream>>>(
      Ebf, RBt, attb, C1p);
  reduce_ln_rt<<<BATCH, 256, 0, stream>>>(C1p, attb, rel_bias, xrt, Xb);
  gemm_ntk64<1><<<dim3(HID / 64, BATCH / 64), 256, 0, stream>>>(
      h0, W1b, b1, nullptr, H1, BATCH, HID, D2);
  gemm_ntk64<1><<<dim3(HID / 64, BATCH / 64), 256, 0, stream>>>(
      H1, W2b, b2, nullptr, H2, BATCH, HID, HID);
  gemm_ntk64<2><<<dim3(D2 / 64, BATCH / 64), 256, 0, stream>>>(
      H2, W0b, b0, G0, nullptr, BATCH, D2, HID);
  ln_rows<<<BATCH, 256, 0, stream>>>(G0, xml, Xb + (size_t)BATCH * D2);
  gemm_ntk64<1><<<dim3(DIM / 64, 2 * BATCH / 64), 256, 0, stream>>>(
      Xb, Wa1b, ba1, nullptr, Aat, 2 * BATCH, DIM, D2);
  gemm_ntk64<2><<<dim3(D2 / 64, 2 * BATCH / 64), 256, 0, stream>>>(
      Aat, Wa2b, ba2, Lg, nullptr, 2 * BATCH, D2, DIM);
  fuse_out<<<BATCH, 256, 0, stream>>>(Lg, xrt, xml, (float*)d_out);
}